// Round 1
// 174.574 us; speedup vs baseline: 1.0235x; 1.0235x over previous
//
#include <hip/hip_runtime.h>

typedef __attribute__((ext_vector_type(8))) short frag8;     // 8 bf16 = 4 VGPRs
typedef __attribute__((ext_vector_type(4))) float f4;
typedef __attribute__((ext_vector_type(4))) unsigned int u4;
typedef __attribute__((ext_vector_type(2))) float f2;

namespace {
constexpr int T_STEPS = 25;
constexpr int IN_F    = 14;
constexpr int H       = 24;
constexpr int NSTEP   = 13;
// Rolling x-staging: 2 buffers x 4 steps x 1024 B per wave (was 13 KiB flat).
constexpr int CHUNK_B  = 4 * 1024;     // one 4-step chunk
constexpr int WAVE_BUF = 2 * CHUNK_B;  // double buffer -> 8 KiB/wave, 16 KiB/block
// Pad-free M=96 layout (6 tiles of 16 rows):
//   tile t<4, row m      -> gate t,   unit m        (m = 0..15)
//   tile 4,  row m       -> gate m&3, unit 16+(m>>2)
//   tile 5,  row m       -> gate m&3, unit 20+(m>>2)
// C/D lane (q=lane>>4, col=lane&15) holds rows m=4q+r -> all 4 gates of units
// {4q+r (r=0..3), 16+q, 20+q} = 6 real units, no padding.
// Wh B-operand k-slot map (k = 8q'+j): j<4 -> unit 4q'+j; j=4 -> 16+q';
// j=5 -> 20+q'; j>=6 -> zero. A lane's OUTPUT units == its own B k-slots
// -> recurrent h stays in registers.
// d_ws: shorts [0..12288): frags ((dir*2+set)*6+tile)*64+lane, 8 shorts.
//   Pre-scaled per gate: i,f,o rows * (-log2e), g rows * (2*log2e).
//   set 0 = Wx: k 0..13 = Wx[f] (x_hi), 14..27 = Wx[f-14] (x_lo),
//           k 28 = bias_hi, 29 = bias_lo, 30..31 = 0
//   set 1 = Wh: k-map above
constexpr float LOG2E    = 1.4426950408889634f;
constexpr float TWOLOG2E = 2.8853900817779268f;
}

#if __has_builtin(__builtin_amdgcn_exp2f)
#define EXP2F(v) __builtin_amdgcn_exp2f(v)
#else
#define EXP2F(v) __expf(0.6931471805599453f * (v))
#endif

__device__ __forceinline__ unsigned short bf16_rne(float f) {
    unsigned int u = __float_as_uint(f);
    u += 0x7fff + ((u >> 16) & 1);
    return (unsigned short)(u >> 16);
}
__device__ __forceinline__ float bf16_to_f(unsigned short s) {
    return __uint_as_float(((unsigned int)s) << 16);
}
__device__ __forceinline__ float fast_rcp(float x) { return __builtin_amdgcn_rcpf(x); }

__global__ void pack_mfma(const float* __restrict__ wif, const float* __restrict__ whf,
                          const float* __restrict__ bif, const float* __restrict__ bhf,
                          const float* __restrict__ wib, const float* __restrict__ whb,
                          const float* __restrict__ bib, const float* __restrict__ bhb,
                          unsigned short* __restrict__ ws)
{
    const int gid = blockIdx.x * 256 + threadIdx.x;
    if (gid >= 1536) return;                 // 2 dir * 2 sets * 6 tiles * 64 lanes
    const int lane = gid & 63;
    const int tile = (gid >> 6) % 6;
    const int set  = (gid / 384) & 1;
    const int dir  = gid / 768;
    const int m = lane & 15, q = lane >> 4;  // A-frag: row-in-tile m, k = q*8+j
    // row -> (gate, unit)
    const int g = (tile < 4) ? tile : (m & 3);
    const int u_row = (tile < 4) ? m : ((tile == 4 ? 16 : 20) + (m >> 2));
    const float* Wx = dir ? wib : wif;
    const float* Wh = dir ? whb : whf;
    const float* bi = dir ? bib : bif;
    const float* bh = dir ? bhb : bhf;
    const int rowW = g * 24 + u_row;         // original weight row
    const float scale = (g == 2) ? TWOLOG2E : -LOG2E;   // g-gate vs i,f,o
    unsigned short vals[8];
    #pragma unroll
    for (int j = 0; j < 8; ++j) {
        const int k = q * 8 + j;
        unsigned short o = 0;
        if (set == 0) {
            if (k < 28) {
                const int f = (k < 14) ? k : k - 14;
                o = bf16_rne(scale * Wx[rowW * IN_F + f]);
            } else if (k < 30) {
                const float b = scale * (bi[rowW] + bh[rowW]);
                const unsigned short hi = bf16_rne(b);
                o = (k == 28) ? hi : bf16_rne(b - bf16_to_f(hi));
            }
        } else {
            const int j7 = k & 7, kq = k >> 3;
            int uh = -1;
            if (j7 < 4)       uh = kq * 4 + j7;
            else if (j7 == 4) uh = 16 + kq;
            else if (j7 == 5) uh = 20 + kq;
            if (uh >= 0) o = bf16_rne(scale * Wh[rowW * H + uh]);
        }
        vals[j] = o;
    }
    unsigned short* d = ws + (size_t)gid * 8;
    #pragma unroll
    for (int j = 0; j < 8; ++j) d[j] = vals[j];
}

__global__ __launch_bounds__(128, 4)
void bilstm_mfma(const float* __restrict__ x, const unsigned short* __restrict__ wpk,
                 const float* __restrict__ head_w, const float* __restrict__ head_b,
                 float* __restrict__ out, int B)
{
    __align__(16) __shared__ unsigned char arena[2 * WAVE_BUF];   // 16 KiB total

    const int tid  = threadIdx.x;
    const int wave = __builtin_amdgcn_readfirstlane(tid >> 6);   // 0 = fwd, 1 = bwd
    const int lane = tid & 63;
    const int q    = lane >> 4;
    const int col  = lane & 15;
    const int b0   = blockIdx.x * 16;

    // resident weight A-fragments: 2 sets x 6 tiles = 48 VGPRs
    frag8 Aw[2][6];
    #pragma unroll
    for (int s = 0; s < 2; ++s)
        #pragma unroll
        for (int t = 0; t < 6; ++t)
            Aw[s][t] = ((const frag8*)wpk)[((wave * 2 + s) * 6 + t) * 64 + lane];

    unsigned char* bufA = arena + wave * WAVE_BUF;
    unsigned char* bufB = bufA + CHUNK_B;

    // ---- rolling x staging: chunk c = steps 4c..4c+3, one lane-task each ----
    // lane -> (slot = lane>>4, elem = lane&15). Chunk 3 has only step 12
    // (lanes >= 16 issue harmless in-bounds loads, skip the write).
    unsigned int L[IN_F];

    auto stage_load = [&](int c, unsigned int* xu) {
        const int si = c * 4 + (lane >> 4);            // <= 15 < T_STEPS: safe
        const int e  = lane & 15;
        const int t  = wave ? (T_STEPS - 1 - si) : si;
        const float* xr = x + ((size_t)(b0 + e) * T_STEPS + t) * IN_F;
        #pragma unroll
        for (int i = 0; i < 7; ++i) {
            f2 v = *(const f2*)(xr + 2 * i);
            xu[2*i] = __float_as_uint(v.x); xu[2*i+1] = __float_as_uint(v.y);
        }
    };

    // frag layout per (step, elem): k 0..13 = x_hi (trunc), 14..27 = x_lo,
    // 28..29 = 1.0 (bias rows in A), 30..31 = 0
    auto stage_write = [&](int c, const unsigned int* xu, unsigned char* buf) {
        if (c == 3 && lane >= 16) return;
        const int sl = lane >> 4;
        const int e  = lane & 15;
        unsigned int lo[IN_F];
        #pragma unroll
        for (int i = 0; i < IN_F; ++i)
            lo[i] = __float_as_uint(__uint_as_float(xu[i])
                                    - __uint_as_float(xu[i] & 0xFFFF0000u));
        unsigned int w[16];
        #pragma unroll
        for (int i = 0; i < 7; ++i)
            w[i] = __builtin_amdgcn_perm(xu[2*i+1], xu[2*i], 0x07060302u);   // {hi16,hi16}
        w[7] = __builtin_amdgcn_perm(lo[1], lo[0], 0x07060302u);
        #pragma unroll
        for (int i = 0; i < 6; ++i)
            w[8 + i] = __builtin_amdgcn_perm(lo[2*i+3], lo[2*i+2], 0x07060302u);
        w[14] = 0x3F803F80u;   // bf16 {1.0, 1.0} -> bias rows in A
        w[15] = 0u;
        #pragma unroll
        for (int qq = 0; qq < 4; ++qq)
            *(u4*)(buf + sl * 1024 + qq * 256 + e * 16) =
                (u4){w[qq*4], w[qq*4+1], w[qq*4+2], w[qq*4+3]};
    };

    f4    cv = {0.f, 0.f, 0.f, 0.f};   // c of units 4q+r
    float c_s[2] = {0.f, 0.f};         // c of units 16+q, 20+q
    f4    Hv;                          // h of units 4q+r (fp32, for head)
    float h_s[2];                      // h of units 16+q, 20+q
    frag8 Bhh, Bhl;                    // recurrent h as B-fragments — registers only
    const f4 zc = {0.f, 0.f, 0.f, 0.f};

    // gates from acc[6]: vector block (units 4q+r: gate g = acc[g], f4 over r)
    // + 2 scalar units (acc[4],acc[5]: gate g = component g).
    // Pre-scaled accs: i,f,o hold -a*log2e; g holds 2a*log2e.
    // c' = (c*(1+ei)(1+eg) + (eg-1)(1+ef)) * rcp((1+ef)(1+ei)(1+eg))
    // h  = (ec-1) * rcp((1+eo)(1+ec)),  ec = exp2(2c'*log2e)
    auto gates = [&](const f4* acc) {
        f4 EI, EF, EG, EO, EC;
        #pragma unroll
        for (int r = 0; r < 4; ++r) {
            EI[r] = EXP2F(acc[0][r]);
            EF[r] = EXP2F(acc[1][r]);
            EG[r] = EXP2F(acc[2][r]);
            EO[r] = EXP2F(acc[3][r]);
        }
        const f4 P  = (EI + 1.0f) * (EG + 1.0f);
        const f4 Df = P * (EF + 1.0f);
        f4 Rf;
        #pragma unroll
        for (int r = 0; r < 4; ++r) Rf[r] = fast_rcp(Df[r]);
        cv = (cv * P + (EG - 1.0f) * (EF + 1.0f)) * Rf;
        #pragma unroll
        for (int r = 0; r < 4; ++r) EC[r] = EXP2F(TWOLOG2E * cv[r]);
        const f4 Do = (EO + 1.0f) * (EC + 1.0f);
        f4 Ro;
        #pragma unroll
        for (int r = 0; r < 4; ++r) Ro[r] = fast_rcp(Do[r]);
        Hv = (EC - 1.0f) * Ro;

        #pragma unroll
        for (int s = 0; s < 2; ++s) {
            const float ei = EXP2F(acc[4 + s][0]);
            const float ef = EXP2F(acc[4 + s][1]);
            const float eg = EXP2F(acc[4 + s][2]);
            const float eo = EXP2F(acc[4 + s][3]);
            const float P2 = (1.0f + ei) * (1.0f + eg);
            const float cn = (c_s[s] * P2 + (eg - 1.0f) * (1.0f + ef))
                             * fast_rcp(P2 * (1.0f + ef));
            c_s[s] = cn;
            const float ec = EXP2F(TWOLOG2E * cn);
            h_s[s] = (ec - 1.0f) * fast_rcp((1.0f + eo) * (1.0f + ec));
        }

        // pack h -> own B-frag k-slots {8q+j}: j0..3 = units 4q+j, j4 = 16+q,
        // j5 = 20+q, j6..7 = zero-weight slots (any value)
        f4 Hl;
        #pragma unroll
        for (int r = 0; r < 4; ++r)
            Hl[r] = Hv[r] - __uint_as_float(__float_as_uint(Hv[r]) & 0xFFFF0000u);
        const float hl4 = h_s[0] - __uint_as_float(__float_as_uint(h_s[0]) & 0xFFFF0000u);
        const float hl5 = h_s[1] - __uint_as_float(__float_as_uint(h_s[1]) & 0xFFFF0000u);
        const u4 uh4 = {
            __builtin_amdgcn_perm(__float_as_uint(Hv[1]), __float_as_uint(Hv[0]), 0x07060302u),
            __builtin_amdgcn_perm(__float_as_uint(Hv[3]), __float_as_uint(Hv[2]), 0x07060302u),
            __builtin_amdgcn_perm(__float_as_uint(h_s[1]), __float_as_uint(h_s[0]), 0x07060302u),
            0u};
        const u4 ul4 = {
            __builtin_amdgcn_perm(__float_as_uint(Hl[1]), __float_as_uint(Hl[0]), 0x07060302u),
            __builtin_amdgcn_perm(__float_as_uint(Hl[3]), __float_as_uint(Hl[2]), 0x07060302u),
            __builtin_amdgcn_perm(__float_as_uint(hl5), __float_as_uint(hl4), 0x07060302u),
            0u};
        Bhh = __builtin_bit_cast(frag8, uh4);
        Bhl = __builtin_bit_cast(frag8, ul4);
    };

    // one full recurrent step from buffer bp, slot r
    auto full_step = [&](const unsigned char* bp, int r) {
        const frag8 Bx = *(const frag8*)(bp + r * 1024 + q * 256 + col * 16);
        f4 acc[6];
        #pragma unroll
        for (int t = 0; t < 6; ++t) {
            acc[t] = __builtin_amdgcn_mfma_f32_16x16x32_bf16(Aw[0][t], Bx,  zc,     0, 0, 0);
            acc[t] = __builtin_amdgcn_mfma_f32_16x16x32_bf16(Aw[1][t], Bhh, acc[t], 0, 0, 0);
            acc[t] = __builtin_amdgcn_mfma_f32_16x16x32_bf16(Aw[1][t], Bhl, acc[t], 0, 0, 0);
        }
        gates(acc);
    };

    // ---- prologue: stage chunk 0 direct, issue chunk-1 loads ----
    stage_load(0, L);
    stage_write(0, L, bufA);
    stage_load(1, L);                  // in flight across steps 0..3

    // ---- step 0 (h = 0: x-product + bias rows only) ----
    {
        const frag8 Bx = *(const frag8*)(bufA + q * 256 + col * 16);
        f4 acc[6];
        #pragma unroll
        for (int t = 0; t < 6; ++t)
            acc[t] = __builtin_amdgcn_mfma_f32_16x16x32_bf16(Aw[0][t], Bx, zc, 0, 0, 0);
        gates(acc);
    }

    // ---- steps 1..3 from chunk 0 ----
    #pragma unroll 1
    for (int r = 1; r < 4; ++r) full_step(bufA, r);

    // ---- chunks 1..2: write staged regs, issue next loads, compute 4 steps ----
    #pragma unroll 1
    for (int cc = 1; cc <= 2; ++cc) {
        unsigned char* wb = (cc & 1) ? bufB : bufA;
        stage_write(cc, L, wb);        // vmcnt-waits loads issued a chunk ago
        stage_load(cc + 1, L);         // cc+1==3: lanes>=16 load harmlessly
        #pragma unroll 1
        for (int r = 0; r < 4; ++r) full_step(wb, r);
    }

    // ---- chunk 3: single step 12 ----
    stage_write(3, L, bufB);
    full_step(bufB, 0);

    // final h (fp32) -> own wave region (x staging is dead)
    // unit u of batch-elem col lives at byte col*96 + u*4
    unsigned char* hbase = arena + wave * WAVE_BUF;
    *(f4*)(hbase + col * 96 + q * 16) = Hv;                       // units 4q+r
    *(float*)(hbase + col * 96 + 64 + q * 4) = h_s[0];            // unit 16+q
    *(float*)(hbase + col * 96 + 80 + q * 4) = h_s[1];            // unit 20+q

    __syncthreads();   // only cross-wave point: head reads both directions' h

    if (tid < 64) {
        const int e = tid >> 2, cls = tid & 3;
        float acc = head_b[cls];
        const float* hf = (const float*)(arena + e * 96);               // fwd
        const float* hb = (const float*)(arena + WAVE_BUF + e * 96);    // bwd
        #pragma unroll
        for (int u = 0; u < H; ++u)
            acc += hf[u] * head_w[cls * 2 * H + u] + hb[u] * head_w[cls * 2 * H + H + u];
        out[(size_t)b0 * 4 + tid] = acc;
    }
}

extern "C" void kernel_launch(void* const* d_in, const int* in_sizes, int n_in,
                              void* d_out, int out_size, void* d_ws, size_t ws_size,
                              hipStream_t stream)
{
    const float* x      = (const float*)d_in[0];
    const float* w_ih_f = (const float*)d_in[1];
    const float* w_hh_f = (const float*)d_in[2];
    const float* b_ih_f = (const float*)d_in[3];
    const float* b_hh_f = (const float*)d_in[4];
    const float* w_ih_b = (const float*)d_in[5];
    const float* w_hh_b = (const float*)d_in[6];
    const float* b_ih_b = (const float*)d_in[7];
    const float* b_hh_b = (const float*)d_in[8];
    const float* head_w = (const float*)d_in[9];
    const float* head_b = (const float*)d_in[10];
    float* out = (float*)d_out;
    unsigned short* ws = (unsigned short*)d_ws;

    const int B = in_sizes[0] / (T_STEPS * IN_F);

    hipLaunchKernelGGL(pack_mfma, dim3(6), dim3(256), 0, stream,
                       w_ih_f, w_hh_f, b_ih_f, b_hh_f,
                       w_ih_b, w_hh_b, b_ih_b, b_hh_b, ws);
    hipLaunchKernelGGL(bilstm_mfma, dim3((B + 15) / 16), dim3(128), 0, stream,
                       x, ws, head_w, head_b, out, B);
}